// Round 1
// baseline (281.676 us; speedup 1.0000x reference)
//
#include <hip/hip_runtime.h>
#include <math.h>

#define BB 512
#define SS 128
#define KK 4
#define HH 128
#define DD 512   // K*H

// ---------------------------------------------------------------------------
// hat[b][k][s][h'] = sum_h item_eb[b][s][h] * w[s][k*HH+h'][h]
// Grid: (4 b-tiles, 4 d-tiles(=capsule), 128 s). Block 256. Tile 128x128, K staged 64.
// LDS layout k-major, stride 132 floats (pad 4 keeps float4 alignment; staging
// writes 2-way conflict = free; frag reads broadcast / 2-way = free).
// ---------------------------------------------------------------------------
__global__ __launch_bounds__(256) void einsum_k(
    const float* __restrict__ item_eb, const float* __restrict__ w,
    float* __restrict__ hat)
{
  __shared__ float Al[64 * 132];
  __shared__ float Wl[64 * 132];
  const int s  = blockIdx.z;
  const int b0 = blockIdx.x * 128;
  const int d0 = blockIdx.y * 128;
  const int kcap = blockIdx.y;
  const int t  = threadIdx.x;
  const int r  = t >> 1;      // 0..127: row within tile
  const int cq = t & 1;       // which 32-float half of the 64-k stage
  const int ty = t >> 4, tx = t & 15;

  float acc[8][8];
  #pragma unroll
  for (int i = 0; i < 8; i++)
    #pragma unroll
    for (int j = 0; j < 8; j++) acc[i][j] = 0.f;

  for (int ks = 0; ks < 128; ks += 64) {
    const float* ga = item_eb + ((size_t)(b0 + r) * SS + s) * HH + ks + cq * 32;
    const float* gw = w + ((size_t)s * DD + d0 + r) * HH + ks + cq * 32;
    #pragma unroll
    for (int j = 0; j < 8; j++) {
      float4 av = *(const float4*)(ga + 4 * j);
      float4 wv = *(const float4*)(gw + 4 * j);
      int kl = cq * 32 + 4 * j;
      Al[(kl + 0) * 132 + r] = av.x; Al[(kl + 1) * 132 + r] = av.y;
      Al[(kl + 2) * 132 + r] = av.z; Al[(kl + 3) * 132 + r] = av.w;
      Wl[(kl + 0) * 132 + r] = wv.x; Wl[(kl + 1) * 132 + r] = wv.y;
      Wl[(kl + 2) * 132 + r] = wv.z; Wl[(kl + 3) * 132 + r] = wv.w;
    }
    __syncthreads();
    #pragma unroll 4
    for (int k = 0; k < 64; k++) {
      float4 a0 = *(const float4*)&Al[k * 132 + ty * 8];
      float4 a1 = *(const float4*)&Al[k * 132 + ty * 8 + 4];
      float4 w0 = *(const float4*)&Wl[k * 132 + tx * 4];        // d = d0 + tx*4 + j
      float4 w1 = *(const float4*)&Wl[k * 132 + 64 + tx * 4];   // d = d0 + 64 + tx*4 + j
      float af[8] = {a0.x, a0.y, a0.z, a0.w, a1.x, a1.y, a1.z, a1.w};
      float wf[8] = {w0.x, w0.y, w0.z, w0.w, w1.x, w1.y, w1.z, w1.w};
      #pragma unroll
      for (int i = 0; i < 8; i++)
        #pragma unroll
        for (int j = 0; j < 8; j++)
          acc[i][j] = fmaf(af[i], wf[j], acc[i][j]);
    }
    __syncthreads();
  }

  #pragma unroll
  for (int i = 0; i < 8; i++) {
    int b = b0 + ty * 8 + i;
    float* o = hat + (((size_t)b * KK + kcap) * SS + s) * HH;
    *(float4*)(o + tx * 4)      = make_float4(acc[i][0], acc[i][1], acc[i][2], acc[i][3]);
    *(float4*)(o + 64 + tx * 4) = make_float4(acc[i][4], acc[i][5], acc[i][6], acc[i][7]);
  }
}

// ---------------------------------------------------------------------------
// Batch-axis softmax (legacy torch dim=0): sw[k][s][b] = softmax_b(cw[k][s][:]),
// then zeroed where mask[b][s]==0. Grid (S, K), block 256 (each thread 2 b's).
// ---------------------------------------------------------------------------
__global__ __launch_bounds__(256) void softmax_k(
    const float* __restrict__ cw, const float* __restrict__ mask,
    float* __restrict__ sw)
{
  __shared__ float rbuf[4];
  const int s = blockIdx.x, k = blockIdx.y, t = threadIdx.x;
  const size_t base = ((size_t)k * SS + s) * BB;
  float v0 = cw[base + t], v1 = cw[base + 256 + t];
  float m = fmaxf(v0, v1);
  #pragma unroll
  for (int o = 32; o; o >>= 1) m = fmaxf(m, __shfl_xor(m, o));
  if ((t & 63) == 0) rbuf[t >> 6] = m;
  __syncthreads();
  m = fmaxf(fmaxf(rbuf[0], rbuf[1]), fmaxf(rbuf[2], rbuf[3]));
  float e0 = expf(v0 - m), e1 = expf(v1 - m);
  float ssum = e0 + e1;
  #pragma unroll
  for (int o = 32; o; o >>= 1) ssum += __shfl_xor(ssum, o);
  __syncthreads();
  if ((t & 63) == 0) rbuf[t >> 6] = ssum;
  __syncthreads();
  float inv = 1.f / (rbuf[0] + rbuf[1] + rbuf[2] + rbuf[3]);
  float m0 = mask[(size_t)t * SS + s];
  float m1 = mask[(size_t)(t + 256) * SS + s];
  sw[base + t]       = (m0 == 0.f) ? 0.f : e0 * inv;
  sw[base + 256 + t] = (m1 == 0.f) ? 0.f : e1 * inv;
}

// ---------------------------------------------------------------------------
// One routing iteration for one (b,k): cap = sum_s sw*hat; squash;
// mode 0: uniform sw (softmax of zeros) from mask, cw = delta   (iter 0)
// mode 1: sw from sw_in,                         cw += delta    (iter 1)
// mode 2: sw from sw_in, write squashed cap to out (no delta)   (iter 2)
// Grid (B, K), block 256. hat tile (64KB) staged in LDS, stride 132.
// ---------------------------------------------------------------------------
__global__ __launch_bounds__(256) void routing_k(
    const float* __restrict__ hat, const float* __restrict__ mask,
    const float* __restrict__ sw_in, float* __restrict__ cw,
    float* __restrict__ out, int mode)
{
  __shared__ float hat_l[128 * 132];
  __shared__ float sw_l[128];
  __shared__ float red[256];
  __shared__ float cq_l[128];
  __shared__ float nshare[2];
  const int b = blockIdx.x, k = blockIdx.y, t = threadIdx.x;

  if (t < 128) {
    if (mode == 0) {
      float m = mask[(size_t)b * SS + t];
      sw_l[t] = (m == 0.f) ? 0.f : (1.f / 512.f);
    } else {
      sw_l[t] = sw_in[((size_t)k * SS + t) * BB + b];
    }
  }
  const float4* hp = (const float4*)(hat + ((size_t)b * KK + k) * SS * HH);
  #pragma unroll
  for (int j = 0; j < 16; j++) {
    int f = t + 256 * j;
    int s = f >> 5, qc = f & 31;
    *(float4*)&hat_l[s * 132 + qc * 4] = hp[f];
  }
  __syncthreads();

  // phase 1: cap[h] = sum_s sw[s] * hat[s][h]  (two s-halves per h)
  {
    const int h = t & 127, half = t >> 7;
    float a = 0.f;
    const float* hl = hat_l + half * 64 * 132 + h;
    #pragma unroll 4
    for (int s8 = 0; s8 < 64; s8++)
      a = fmaf(sw_l[half * 64 + s8], hl[s8 * 132], a);
    red[t] = a;
  }
  __syncthreads();
  float cap = 0.f;
  if (t < 128) cap = red[t] + red[t + 128];
  float sq = cap * cap;
  #pragma unroll
  for (int o = 32; o; o >>= 1) sq += __shfl_xor(sq, o);
  if (t < 128 && (t & 63) == 0) nshare[t >> 6] = sq;
  __syncthreads();
  const float n = nshare[0] + nshare[1];
  const float fac = n / (1.f + n) / sqrtf(n + 1e-9f);
  if (t < 128) {
    float cq = cap * fac;
    cq_l[t] = cq;
    if (mode == 2) out[((size_t)b * KK + k) * HH + t] = cq;
  }
  __syncthreads();

  if (mode < 2) {
    // phase 2: delta[s] = dot(hat[s][:], cq)   — pair of lanes per s
    const int s = t >> 1, hh = t & 1;
    const float4* row = (const float4*)(hat_l + s * 132);
    const float4* cv  = (const float4*)cq_l;
    float d = 0.f;
    #pragma unroll
    for (int j = 0; j < 16; j++) {
      float4 v = row[hh * 16 + j];
      float4 c = cv[hh * 16 + j];
      d += v.x * c.x + v.y * c.y + v.z * c.z + v.w * c.w;
    }
    d += __shfl_xor(d, 1);
    if (hh == 0) {
      float* p = cw + ((size_t)k * SS + s) * BB + b;
      if (mode == 0) *p = d; else *p += d;
    }
  }
}

extern "C" void kernel_launch(void* const* d_in, const int* in_sizes, int n_in,
                              void* d_out, int out_size, void* d_ws, size_t ws_size,
                              hipStream_t stream) {
  const float* item_eb = (const float*)d_in[0];   // [B,S,H]
  const float* mask    = (const float*)d_in[1];   // [B,S]
  const float* w       = (const float*)d_in[2];   // [1,S,K*H,H]
  float* out = (float*)d_out;                     // [B,K,H]

  char* ws = (char*)d_ws;
  float* hat = (float*)ws;                                        // [B,K,S,H] 134 MB
  float* cw  = (float*)(ws + (size_t)BB * KK * SS * HH * 4);      // [K,S,B] 1 MB
  float* swb = cw + (size_t)KK * SS * BB;                         // [K,S,B] 1 MB

  einsum_k<<<dim3(4, 4, 128), 256, 0, stream>>>(item_eb, w, hat);
  // iter 0: softmax(zeros) == 1/B uniform -> folded into routing kernel
  routing_k<<<dim3(BB, KK), 256, 0, stream>>>(hat, mask, nullptr, cw, out, 0);
  softmax_k<<<dim3(SS, KK), 256, 0, stream>>>(cw, mask, swb);
  routing_k<<<dim3(BB, KK), 256, 0, stream>>>(hat, mask, swb, cw, out, 1);
  softmax_k<<<dim3(SS, KK), 256, 0, stream>>>(cw, mask, swb);
  routing_k<<<dim3(BB, KK), 256, 0, stream>>>(hat, mask, swb, cw, out, 2);
}

// Round 2
// 198.373 us; speedup vs baseline: 1.4199x; 1.4199x over previous
//
#include <hip/hip_runtime.h>
#include <math.h>

#define BB 512
#define SS 128
#define KK 4
#define HH 128
#define DD 512   // K*H

typedef __attribute__((ext_vector_type(8))) short bf16x8;
typedef __attribute__((ext_vector_type(4))) float f32x4;

__device__ __forceinline__ unsigned short f2bf(float f) {
  unsigned u = __float_as_uint(f);
  unsigned r = u + 0x7fffu + ((u >> 16) & 1u);   // RNE (no NaNs in this data)
  return (unsigned short)(r >> 16);
}
__device__ __forceinline__ float bfhi(unsigned u) {   // high 16 bits are a bf16
  return __uint_as_float(u & 0xffff0000u);
}
__device__ __forceinline__ float bflo(unsigned u) {   // low 16 bits are a bf16
  return __uint_as_float(u << 16);
}

// ---------------------------------------------------------------------------
// fp32 -> bf16 bulk convert (RNE). n4 = element_count/4.
// ---------------------------------------------------------------------------
__global__ __launch_bounds__(256) void cvt_k(
    const float* __restrict__ in, unsigned short* __restrict__ out, int n4)
{
  int i = blockIdx.x * 256 + threadIdx.x;
  if (i < n4) {
    float4 v = ((const float4*)in)[i];
    ushort4 o;
    o.x = f2bf(v.x); o.y = f2bf(v.y); o.z = f2bf(v.z); o.w = f2bf(v.w);
    ((ushort4*)out)[i] = o;
  }
}

// ---------------------------------------------------------------------------
// hat[b][k][s][h'] = sum_h item[b][s][h] * w[s][k*HH+h'][h]   (bf16 in/out)
// Per block: one s, 128x128 output tile, K=128 contraction, single LDS stage.
// mfma_f32_16x16x32_bf16; A[m=lane&15][k=quad*8+j]; C/D col=lane&15,
// row=quad*4+reg (HW-verified layouts). LDS stride 136 bf16 (pad 8): frag
// reads ~2-way (free), staging writes 2-way (free).
// ---------------------------------------------------------------------------
__global__ __launch_bounds__(256) void einsum_mfma(
    const unsigned short* __restrict__ A,   // item bf16 [B][S][H]
    const unsigned short* __restrict__ W,   // w    bf16 [S][D][H]
    unsigned short* __restrict__ hat)       // bf16 [B][K][S][H]
{
  __shared__ unsigned short Al[128 * 136];
  __shared__ unsigned short Wl[128 * 136];
  const int s  = blockIdx.z;
  const int b0 = blockIdx.x * 128;
  const int dt = blockIdx.y;
  const int d0 = dt * 128;
  const int t  = threadIdx.x;

  // stage both 128x128 bf16 tiles (8 x 16B per thread per array)
  #pragma unroll
  for (int j = 0; j < 8; j++) {
    int f = t + 256 * j;          // 0..2047
    int r = f >> 4, c = f & 15;   // row, 16B-col
    const uint4* ga = (const uint4*)(A + ((size_t)(b0 + r) * SS + s) * HH);
    const uint4* gw = (const uint4*)(W + ((size_t)s * DD + d0 + r) * HH);
    *(uint4*)&Al[r * 136 + c * 8] = ga[c];
    *(uint4*)&Wl[r * 136 + c * 8] = gw[c];
  }
  __syncthreads();

  const int lane = t & 63, wv = t >> 6;
  const int qm = wv & 1, qn = wv >> 1;        // wave quadrant (64x64)
  const int n16 = lane & 15, kq = lane >> 4;  // in-tile col / k-quad

  f32x4 acc[4][4] = {};
  #pragma unroll
  for (int kk = 0; kk < 4; kk++) {
    const int kbase = kk * 32 + kq * 8;
    bf16x8 af[4], bf[4];
    #pragma unroll
    for (int i = 0; i < 4; i++) {
      af[i] = *(const bf16x8*)&Al[(qm * 64 + i * 16 + n16) * 136 + kbase];
      bf[i] = *(const bf16x8*)&Wl[(qn * 64 + i * 16 + n16) * 136 + kbase];
    }
    #pragma unroll
    for (int i = 0; i < 4; i++)
      #pragma unroll
      for (int j = 0; j < 4; j++)
        acc[i][j] = __builtin_amdgcn_mfma_f32_16x16x32_bf16(af[i], bf[j], acc[i][j], 0, 0, 0);
  }

  // epilogue: D row = kq*4+reg (b), col = n16 (h'); store bf16
  #pragma unroll
  for (int i = 0; i < 4; i++) {
    #pragma unroll
    for (int reg = 0; reg < 4; reg++) {
      int b = b0 + qm * 64 + i * 16 + kq * 4 + reg;
      unsigned short* orow = hat + (((size_t)b * KK + dt) * SS + s) * HH;
      #pragma unroll
      for (int j = 0; j < 4; j++)
        orow[qn * 64 + j * 16 + n16] = f2bf(acc[i][j][reg]);
    }
  }
}

// ---------------------------------------------------------------------------
// Batch-axis softmax (legacy torch dim=0) + mask zeroing. Grid (S,K).
// ---------------------------------------------------------------------------
__global__ __launch_bounds__(256) void softmax_k(
    const float* __restrict__ cw, const float* __restrict__ mask,
    float* __restrict__ sw)
{
  __shared__ float rbuf[4];
  const int s = blockIdx.x, k = blockIdx.y, t = threadIdx.x;
  const size_t base = ((size_t)k * SS + s) * BB;
  float v0 = cw[base + t], v1 = cw[base + 256 + t];
  float m = fmaxf(v0, v1);
  #pragma unroll
  for (int o = 32; o; o >>= 1) m = fmaxf(m, __shfl_xor(m, o));
  if ((t & 63) == 0) rbuf[t >> 6] = m;
  __syncthreads();
  m = fmaxf(fmaxf(rbuf[0], rbuf[1]), fmaxf(rbuf[2], rbuf[3]));
  float e0 = expf(v0 - m), e1 = expf(v1 - m);
  float ssum = e0 + e1;
  #pragma unroll
  for (int o = 32; o; o >>= 1) ssum += __shfl_xor(ssum, o);
  __syncthreads();
  if ((t & 63) == 0) rbuf[t >> 6] = ssum;
  __syncthreads();
  float inv = 1.f / (rbuf[0] + rbuf[1] + rbuf[2] + rbuf[3]);
  float m0 = mask[(size_t)t * SS + s];
  float m1 = mask[(size_t)(t + 256) * SS + s];
  sw[base + t]       = (m0 == 0.f) ? 0.f : e0 * inv;
  sw[base + 256 + t] = (m1 == 0.f) ? 0.f : e1 * inv;
}

// ---------------------------------------------------------------------------
// One routing iteration per (b,k). No hat LDS stage — stream bf16 hat from
// L3 twice (phase1 coalesced over h, phase2 row-dot per s). LDS tiny -> 8
// blocks/CU.
//   mode 0: uniform sw from mask, cw  = delta
//   mode 1: sw from sw_in,        cw += delta
//   mode 2: sw from sw_in,        out = squash(cap)
// ---------------------------------------------------------------------------
__global__ __launch_bounds__(256) void routing_k(
    const unsigned short* __restrict__ hat, const float* __restrict__ mask,
    const float* __restrict__ sw_in, float* __restrict__ cw,
    float* __restrict__ out, int mode)
{
  __shared__ float sw_l[128];
  __shared__ float4 red4[8][33];
  __shared__ float cq_l[128];
  const int b = blockIdx.x, k = blockIdx.y, t = threadIdx.x;

  if (t < 128) {
    if (mode == 0) {
      sw_l[t] = (mask[(size_t)b * SS + t] == 0.f) ? 0.f : (1.f / 512.f);
    } else {
      sw_l[t] = sw_in[((size_t)k * SS + t) * BB + b];
    }
  }
  __syncthreads();

  const unsigned short* hrow = hat + ((size_t)b * KK + k) * SS * HH;

  // phase 1: cap[h] = sum_s sw[s] * hat[s][h]
  {
    const int h4 = t & 31, sg = t >> 5;          // 32 float4-cols x 8 s-groups
    const uint2* hp = (const uint2*)hrow;        // 32 x (4 bf16) per s-row
    float4 a = make_float4(0.f, 0.f, 0.f, 0.f);
    #pragma unroll 4
    for (int i = 0; i < 16; i++) {
      int s = sg * 16 + i;
      uint2 v = hp[s * 32 + h4];
      float wv = sw_l[s];
      a.x = fmaf(wv, bflo(v.x), a.x);
      a.y = fmaf(wv, bfhi(v.x), a.y);
      a.z = fmaf(wv, bflo(v.y), a.z);
      a.w = fmaf(wv, bfhi(v.y), a.w);
    }
    red4[sg][h4] = a;
  }
  __syncthreads();

  if (t < 32) {
    float4 cap = red4[0][t];
    #pragma unroll
    for (int sg = 1; sg < 8; sg++) {
      float4 r = red4[sg][t];
      cap.x += r.x; cap.y += r.y; cap.z += r.z; cap.w += r.w;
    }
    float sq = cap.x * cap.x + cap.y * cap.y + cap.z * cap.z + cap.w * cap.w;
    #pragma unroll
    for (int o = 16; o; o >>= 1) sq += __shfl_xor(sq, o);
    const float n = sq;
    const float fac = n / (1.f + n) / sqrtf(n + 1e-9f);
    cap.x *= fac; cap.y *= fac; cap.z *= fac; cap.w *= fac;
    ((float4*)cq_l)[t] = cap;
    if (mode == 2)
      ((float4*)(out + ((size_t)b * KK + k) * HH))[t] = cap;
  }
  __syncthreads();

  if (mode < 2) {
    // phase 2: delta[s] = dot(hat[s][:], cq) — lane pair per s
    const int s = t >> 1, hh = t & 1;
    const uint4* hp16 = (const uint4*)hrow;      // 16 x (8 bf16) per s-row
    float d = 0.f;
    #pragma unroll
    for (int j = 0; j < 8; j++) {
      uint4 v = hp16[s * 16 + hh * 8 + j];
      const float* cq = cq_l + hh * 64 + j * 8;
      d += bflo(v.x) * cq[0] + bfhi(v.x) * cq[1]
         + bflo(v.y) * cq[2] + bfhi(v.y) * cq[3]
         + bflo(v.z) * cq[4] + bfhi(v.z) * cq[5]
         + bflo(v.w) * cq[6] + bfhi(v.w) * cq[7];
    }
    d += __shfl_xor(d, 1);
    if (hh == 0) {
      float* p = cw + ((size_t)k * SS + s) * BB + b;
      if (mode == 0) *p = d; else *p += d;
    }
  }
}

extern "C" void kernel_launch(void* const* d_in, const int* in_sizes, int n_in,
                              void* d_out, int out_size, void* d_ws, size_t ws_size,
                              hipStream_t stream) {
  const float* item_eb = (const float*)d_in[0];   // [B,S,H]
  const float* mask    = (const float*)d_in[1];   // [B,S]
  const float* w       = (const float*)d_in[2];   // [1,S,K*H,H]
  float* out = (float*)d_out;                     // [B,K,H]

  char* ws = (char*)d_ws;
  unsigned short* hat_bf  = (unsigned short*)ws;                       // 67.1 MB
  unsigned short* item_bf = (unsigned short*)(ws + 67108864);          // 16.8 MB
  unsigned short* w_bf    = (unsigned short*)(ws + 83886080);          // 16.8 MB
  float* cw  = (float*)(ws + 100663296);                               // 1 MB
  float* swb = (float*)(ws + 101711872);                               // 1 MB

  const int n4 = (BB * SS * HH) / 4;  // == (SS * DD * HH) / 4 == 2097152
  cvt_k<<<dim3(n4 / 256), 256, 0, stream>>>(item_eb, item_bf, n4);
  cvt_k<<<dim3(n4 / 256), 256, 0, stream>>>(w, w_bf, n4);

  einsum_mfma<<<dim3(4, 4, 128), 256, 0, stream>>>(item_bf, w_bf, hat_bf);

  routing_k<<<dim3(BB, KK), 256, 0, stream>>>(hat_bf, mask, nullptr, cw, out, 0);
  softmax_k<<<dim3(SS, KK), 256, 0, stream>>>(cw, mask, swb);
  routing_k<<<dim3(BB, KK), 256, 0, stream>>>(hat_bf, mask, swb, cw, out, 1);
  softmax_k<<<dim3(SS, KK), 256, 0, stream>>>(cw, mask, swb);
  routing_k<<<dim3(BB, KK), 256, 0, stream>>>(hat_bf, mask, swb, cw, out, 2);
}